// Round 2
// 961.168 us; speedup vs baseline: 1.0953x; 1.0953x over previous
//
#include <hip/hip_runtime.h>
#include <stdint.h>

// Problem constants: B=64, T=64, C=4096, H=64, hd=64, rank=1, scale=0.125
#define M_TOK   4096      // B*T
#define C_DIM   4096
#define N_QKV   12288
#define KD      4096      // K for both GEMMs
#define NT2     32        // (KD/64)/2 iterations, 2 K-tiles each

typedef __bf16 bf16x8 __attribute__((ext_vector_type(8)));
typedef float  f32x4  __attribute__((ext_vector_type(4)));
typedef unsigned short ushort8 __attribute__((ext_vector_type(8)));

__device__ __forceinline__ unsigned short f2bf(float f) {
  unsigned int u = __builtin_bit_cast(unsigned int, f);
  u = (u + 0x7FFFu + ((u >> 16) & 1u)) >> 16;   // RNE
  return (unsigned short)u;
}
__device__ __forceinline__ float bf2f(unsigned short h) {
  unsigned int u = ((unsigned int)h) << 16;
  return __builtin_bit_cast(float, u);
}

// ---------------- fp32 -> bf16 conversion (16B out per thread) ----------------
__global__ __launch_bounds__(256) void cvt_f32_bf16(const float* __restrict__ in,
                                                    unsigned short* __restrict__ out,
                                                    int n16) {  // n16 = elems/8
  int idx = blockIdx.x * 256 + threadIdx.x;
  if (idx >= n16) return;
  const float4* p = (const float4*)in;
  float4 a = p[idx * 2], b = p[idx * 2 + 1];
  uint4 r;
  r.x = (unsigned)f2bf(a.x) | ((unsigned)f2bf(a.y) << 16);
  r.y = (unsigned)f2bf(a.z) | ((unsigned)f2bf(a.w) << 16);
  r.z = (unsigned)f2bf(b.x) | ((unsigned)f2bf(b.y) << 16);
  r.w = (unsigned)f2bf(b.z) | ((unsigned)f2bf(b.w) << 16);
  ((uint4*)out)[idx] = r;
}

#define GLLDS(gp, lp) \
  __builtin_amdgcn_global_load_lds((const __attribute__((address_space(1))) unsigned int*)(gp), \
                                   (__attribute__((address_space(3))) unsigned int*)(lp), 16, 0, 0)

// =====================================================================
// 256x256 8-phase bf16 NT GEMM (C = A[M,K] * B[N,K]^T + bias), K=4096.
// 512 threads = 8 waves (2M x 4N); per-wave output 128x64; BK=64.
// LDS 128 KiB STATIC (no dynamic-LDS attribute games under graph capture):
// A/B K-tile double buffer. Tile t -> buf[t&1].
//
// LDS layout (elements):
//   As[buf][hf][i2][64][64]: stage S(hf): instr1 -> (i2=0, rows hf*64+[0,64)),
//                             instr2 -> (i2=1, same rows +128 in global).
//     reader (wm, mh): offset mh*8192 + wm*4096; row mt*16+lr.
//   Bs[buf][nhf][i2][u][32][64]: stage T(nhf): thread t covers u=t>>8,
//     rr=(t>>3)&31; reader (wn, nhf): offset nhf*8192 + wn*2048; row nt*16+lr.
//
// XOR swizzle (T2, G21 both-sides): LDS(row, chunk c) holds global chunk
// c^(row&7) — applied by pre-swizzling the GLOBAL source column, undone on
// the ds_read side (ck0 = (lq ^ (lr&7))*8, ck1 = ck0^32).
//
// Phase schedule per iteration i (tiles 2i [buf0, P1-4], 2i+1 [buf1, P5-8]):
//   P1: rd A(b0,mh0)+B(b0,n0)  stage S1(2i+1)  mfma Q(0,0)
//   P2: rd B(b0,n1)            stage S0(2i+2)  mfma Q(0,1)
//   P3: rd A(b0,mh1)           stage T0(2i+2)  mfma Q(1,0)
//   P4: -                      stage T1(2i+2)  mfma Q(1,1)  vmcnt(6)
//   P5: rd A(b1,mh0)+B(b1,n0)  stage S1(2i+2)  mfma Q(0,0)
//   P6: rd B(b1,n1)            stage S0(2i+3)  mfma Q(0,1)
//   P7: rd A(b1,mh1)           stage T0(2i+3)  mfma Q(1,0)
//   P8: -                      stage T1(2i+3)  mfma Q(1,1)  vmcnt(6)
// RAW: every read region retired by a vmcnt(6) >=4 half-tiles after its stage.
// WAR: every stage issued >=1 barrier-phase after the last read of its region.
// vmcnt never drains to 0 in the loop (T4); 3 half-tiles stay in flight.
// Tail stages clamp to tile 63 (dead data into dead regions, in-bounds).
// =====================================================================

#define STAGE_A(buf, hf, tau) do {                                         \
    const unsigned short* g_ = Ag + (size_t)((hf) * 64) * KD + (tau) * 64; \
    unsigned short* d_ = As + (buf) * 16384 + (hf) * 8192 + t * 8;         \
    GLLDS(g_, d_);                                                         \
    GLLDS(g_ + (size_t)128 * KD, d_ + 4096);                               \
  } while (0)

#define STAGE_B(buf, nhf, tau) do {                                         \
    const unsigned short* g_ = Bg + (size_t)((nhf) * 32) * KD + (tau) * 64; \
    unsigned short* d_ = Bs + (buf) * 16384 + (nhf) * 8192 + t * 8;         \
    GLLDS(g_, d_);                                                          \
    GLLDS(g_ + (size_t)128 * KD, d_ + 4096);                                \
  } while (0)

#define LDA_(buf, mh) do {                                                        \
    const unsigned short* pa_ = As + (buf) * 16384 + (mh) * 8192 + wm * 4096 + lr * 64; \
    _Pragma("unroll") for (int mt_ = 0; mt_ < 4; ++mt_) {                         \
      afk[0][mt_] = *(const bf16x8*)(pa_ + mt_ * 1024 + ck0);                     \
      afk[1][mt_] = *(const bf16x8*)(pa_ + mt_ * 1024 + ck1);                     \
    }                                                                             \
  } while (0)

#define LDB_(buf, nhf, dst) do {                                                  \
    const unsigned short* pb_ = Bs + (buf) * 16384 + (nhf) * 8192 + wn * 2048 + lr * 64; \
    _Pragma("unroll") for (int nt_ = 0; nt_ < 2; ++nt_) {                         \
      dst[0][nt_] = *(const bf16x8*)(pb_ + nt_ * 1024 + ck0);                     \
      dst[1][nt_] = *(const bf16x8*)(pb_ + nt_ * 1024 + ck1);                     \
    }                                                                             \
  } while (0)

#define QUAD_(mh, nhf, bsrc) do {                                                 \
    _Pragma("unroll") for (int kk_ = 0; kk_ < 2; ++kk_)                           \
    _Pragma("unroll") for (int mt_ = 0; mt_ < 4; ++mt_)                           \
    _Pragma("unroll") for (int nt_ = 0; nt_ < 2; ++nt_)                           \
      acc[mh][nhf][mt_][nt_] = __builtin_amdgcn_mfma_f32_16x16x32_bf16(           \
          afk[kk_][mt_], bsrc[kk_][nt_], acc[mh][nhf][mt_][nt_], 0, 0, 0);        \
  } while (0)

// phase mid: barrier, drain LDS reads, boost prio for MFMA cluster (T5)
#define PH_MID() do {                                      \
    asm volatile("" ::: "memory");                         \
    __builtin_amdgcn_s_barrier();                          \
    asm volatile("s_waitcnt lgkmcnt(0)" ::: "memory");     \
    __builtin_amdgcn_s_setprio(1);                         \
  } while (0)

#define PH_END() do {                                      \
    __builtin_amdgcn_s_setprio(0);                         \
    asm volatile("" ::: "memory");                         \
    __builtin_amdgcn_s_barrier();                          \
    asm volatile("" ::: "memory");                         \
  } while (0)

// counted vmcnt (T4): 3 half-tiles (6 loads) stay in flight across barrier
#define PH_END_VM() do {                                   \
    __builtin_amdgcn_s_setprio(0);                         \
    asm volatile("s_waitcnt vmcnt(6)" ::: "memory");       \
    __builtin_amdgcn_s_barrier();                          \
    asm volatile("" ::: "memory");                         \
  } while (0)

template <int OUT_BF16>
__global__ __launch_bounds__(512, 2) void gemm256(const unsigned short* __restrict__ A,
                                                  const unsigned short* __restrict__ B,
                                                  const float* __restrict__ bias,
                                                  void* __restrict__ Cptr,
                                                  int N) {
  // 128 KiB static LDS (gfx950: 160 KiB/CU available) — 1 block/CU, 8 waves
  __shared__ __align__(16) unsigned short As[32768];
  __shared__ __align__(16) unsigned short Bs[32768];

  const int t   = threadIdx.x;
  const int nwg = gridDim.x;
  const int bid = blockIdx.x;
  // T1: bijective XCD swizzle (nwg % 8 == 0 for all our launches)
  const int wg  = (bid & 7) * (nwg >> 3) + (bid >> 3);
  const int bm  = wg & 15;             // M/256 == 16 always; bn-major chunks
  const int bn  = wg >> 4;             // -> per-XCD B-panel reuse in its L2

  const int w  = t >> 6, l = t & 63;
  const int wm = w >> 2, wn = w & 3;   // 2M x 4N wave grid
  const int lr = l & 15, lq = l >> 4;
  const int ck0 = (lq ^ (lr & 7)) * 8; // un-swizzled read chunk, kk=0
  const int ck1 = ck0 ^ 32;            // kk=1 (chunk ^ 4 -> elems ^ 32)

  // staging thread-constants: thread t covers row r8=t>>3, source chunk
  // pre-swizzled so LDS(row,c) = global chunk c^(row&7)  [G21: both sides]
  const int r8  = t >> 3;
  const int kcs = ((t & 7) ^ (r8 & 7)) * 8;
  const unsigned short* Ag = A + (size_t)(bm * 256 + r8) * KD + kcs;
  const unsigned short* Bg = B + (size_t)(bn * 256 + ((t >> 8) << 6) + (r8 & 31)) * KD + kcs;

  f32x4 acc[2][2][4][2] = {};          // [mh][nhf][mt][nt] = 128 VGPR
  bf16x8 afk[2][4], bA[2][2], bB[2][2];

  // prologue: tile0 {S0,T0,T1,S1}, tile1 {S0,T0,T1}; tile0 landed, 3 in flight
  STAGE_A(0, 0, 0); STAGE_B(0, 0, 0); STAGE_B(0, 1, 0); STAGE_A(0, 1, 0);
  STAGE_A(1, 0, 1); STAGE_B(1, 0, 1); STAGE_B(1, 1, 1);
  asm volatile("s_waitcnt vmcnt(6)" ::: "memory");
  __builtin_amdgcn_s_barrier();
  asm volatile("" ::: "memory");

#pragma unroll 1
  for (int i = 0; i < NT2; ++i) {
    const int t1 = 2 * i + 1;
    const int t2 = (2 * i + 2 < 64) ? 2 * i + 2 : 63;   // clamp: dead stages
    const int t3 = (2 * i + 3 < 64) ? 2 * i + 3 : 63;
    // P1
    LDA_(0, 0); LDB_(0, 0, bA);
    STAGE_A(1, 1, t1);
    PH_MID(); QUAD_(0, 0, bA); PH_END();
    // P2
    LDB_(0, 1, bB);
    STAGE_A(0, 0, t2);
    PH_MID(); QUAD_(0, 1, bB); PH_END();
    // P3
    LDA_(0, 1);
    STAGE_B(0, 0, t2);
    PH_MID(); QUAD_(1, 0, bA); PH_END();
    // P4
    STAGE_B(0, 1, t2);
    PH_MID(); QUAD_(1, 1, bB); PH_END_VM();
    // P5
    LDA_(1, 0); LDB_(1, 0, bA);
    STAGE_A(0, 1, t2);
    PH_MID(); QUAD_(0, 0, bA); PH_END();
    // P6
    LDB_(1, 1, bB);
    STAGE_A(1, 0, t3);
    PH_MID(); QUAD_(0, 1, bB); PH_END();
    // P7
    LDA_(1, 1);
    STAGE_B(1, 0, t3);
    PH_MID(); QUAD_(1, 0, bA); PH_END();
    // P8
    STAGE_B(1, 1, t3);
    PH_MID(); QUAD_(1, 1, bB); PH_END_VM();
  }

  // drain the 6 in-flight LDS-DMA loads before waves can exit (s_endpgm with
  // outstanding global_load_lds would write into a deallocated LDS aperture)
  asm volatile("s_waitcnt vmcnt(0)" ::: "memory");

  // epilogue: C/D layout col=lane&15, row=(lane>>4)*4+reg
  const int row0 = bm * 256 + wm * 128 + lq * 4;
  const int col0 = bn * 256 + wn * 64 + lr;
#pragma unroll
  for (int nhf = 0; nhf < 2; ++nhf)
#pragma unroll
    for (int nt = 0; nt < 2; ++nt) {
      const int col = col0 + nhf * 32 + nt * 16;
      const float bv = bias[col];
#pragma unroll
      for (int mh = 0; mh < 2; ++mh)
#pragma unroll
        for (int mt = 0; mt < 4; ++mt) {
          const int row = row0 + mh * 64 + mt * 16;
#pragma unroll
          for (int rg = 0; rg < 4; ++rg) {
            float v = acc[mh][nhf][mt][nt][rg] + bv;
            if (OUT_BF16)
              ((unsigned short*)Cptr)[(size_t)(row + rg) * N + col] = f2bf(v);
            else
              ((float*)Cptr)[(size_t)(row + rg) * N + col] = v;
          }
        }
    }
}

// ---------------- head-mixing attention, MFMA, one WAVE per (b,t) -------------
// (unchanged — not the bottleneck this round)
#define AST 72   // padded LDS row stride (elements)

__global__ __launch_bounds__(64) void attn_mfma(const unsigned short* __restrict__ qkv,
                                                unsigned short* __restrict__ y) {
  __shared__ __align__(16) unsigned short Ks[64 * AST];   // K, later P
  __shared__ __align__(16) unsigned short Vs[64 * AST];
  const int l  = threadIdx.x;
  const int lr = l & 15;
  const int lq = l >> 4;
  const size_t base = (size_t)blockIdx.x * 12288;

  // ---- stage K,V (coalesced 16B loads, padded LDS rows) ----
  {
    const int jr = l >> 3;          // 0..7
    const int cc = (l & 7) * 8;     // col chunk (elements)
#pragma unroll
    for (int c = 0; c < 8; ++c) {
      const int j = c * 8 + jr;
      *(uint4*)(Ks + j * AST + cc) = *(const uint4*)(qkv + base + 4096 + (size_t)j * 64 + cc);
      *(uint4*)(Vs + j * AST + cc) = *(const uint4*)(qkv + base + 8192 + (size_t)j * 64 + cc);
    }
  }

  // ---- Q A-frags direct from global ----
  bf16x8 aq[4][2];
#pragma unroll
  for (int it = 0; it < 4; ++it)
#pragma unroll
    for (int kk = 0; kk < 2; ++kk)
      aq[it][kk] = *(const bf16x8*)(qkv + base + (size_t)(it * 16 + lr) * 64 + kk * 32 + lq * 8);

  __syncthreads();

  // ---- S = Q K^T ----
  f32x4 acc[4][4] = {};
#pragma unroll
  for (int kk = 0; kk < 2; ++kk) {
    bf16x8 bk[4];
#pragma unroll
    for (int jt = 0; jt < 4; ++jt)
      bk[jt] = *(const bf16x8*)(Ks + (jt * 16 + lr) * AST + kk * 32 + lq * 8);
#pragma unroll
    for (int it = 0; it < 4; ++it)
#pragma unroll
      for (int jt = 0; jt < 4; ++jt)
        acc[it][jt] = __builtin_amdgcn_mfma_f32_16x16x32_bf16(aq[it][kk], bk[jt], acc[it][jt], 0, 0, 0);
  }

  // ---- mask + softmax in-register ----
#pragma unroll
  for (int it = 0; it < 4; ++it) {
#pragma unroll
    for (int rg = 0; rg < 4; ++rg) {
      const int row = it * 16 + lq * 4 + rg;
      float mx = -1e30f;
#pragma unroll
      for (int jt = 0; jt < 4; ++jt) {
        const int col = jt * 16 + lr;
        float s = acc[it][jt][rg] * 0.125f;
        s = (col <= row) ? s : -1e30f;
        acc[it][jt][rg] = s;
        mx = fmaxf(mx, s);
      }
#pragma unroll
      for (int d = 1; d < 16; d <<= 1)
        mx = fmaxf(mx, __shfl_xor(mx, d));
      float sum = 0.f;
#pragma unroll
      for (int jt = 0; jt < 4; ++jt) {
        float e = __expf(acc[it][jt][rg] - mx);
        acc[it][jt][rg] = e;
        sum += e;
      }
#pragma unroll
      for (int d = 1; d < 16; d <<= 1)
        sum += __shfl_xor(sum, d);
      const float inv = 1.f / sum;
#pragma unroll
      for (int jt = 0; jt < 4; ++jt)
        acc[it][jt][rg] *= inv;
    }
  }

  // ---- P -> LDS (bf16), reusing K slab ----
#pragma unroll
  for (int it = 0; it < 4; ++it)
#pragma unroll
    for (int rg = 0; rg < 4; ++rg) {
      const int row = it * 16 + lq * 4 + rg;
#pragma unroll
      for (int jt = 0; jt < 4; ++jt)
        Ks[row * AST + jt * 16 + lr] = f2bf(acc[it][jt][rg]);
    }
  __syncthreads();

  // ---- Y = P V ----
  f32x4 out[4][4] = {};
#pragma unroll
  for (int kk = 0; kk < 2; ++kk) {
    bf16x8 ap[4];
#pragma unroll
    for (int it = 0; it < 4; ++it)
      ap[it] = *(const bf16x8*)(Ks + (it * 16 + lr) * AST + kk * 32 + lq * 8);
#pragma unroll
    for (int dt = 0; dt < 4; ++dt) {
      ushort8 vt;
#pragma unroll
      for (int jj = 0; jj < 8; ++jj)
        vt[jj] = Vs[(kk * 32 + lq * 8 + jj) * AST + dt * 16 + lr];
      const bf16x8 bv = __builtin_bit_cast(bf16x8, vt);
#pragma unroll
      for (int it = 0; it < 4; ++it)
        out[it][dt] = __builtin_amdgcn_mfma_f32_16x16x32_bf16(ap[it], bv, out[it][dt], 0, 0, 0);
    }
  }

  // ---- epilogue: y[bt][i*64+d] bf16 ----
  unsigned short* yrow = y + (size_t)blockIdx.x * 4096;
#pragma unroll
  for (int it = 0; it < 4; ++it)
#pragma unroll
    for (int rg = 0; rg < 4; ++rg) {
      const int i = it * 16 + lq * 4 + rg;
#pragma unroll
      for (int dt = 0; dt < 4; ++dt)
        yrow[i * 64 + dt * 16 + lr] = f2bf(out[it][dt][rg]);
    }
}

// ---------------- launch ------------------------------------------------------
extern "C" void kernel_launch(void* const* d_in, const int* in_sizes, int n_in,
                              void* d_out, int out_size, void* d_ws, size_t ws_size,
                              hipStream_t stream) {
  const float* x  = (const float*)d_in[0];   // (64,64,4096)
  const float* Wa = (const float*)d_in[1];   // (12288,4096)
  const float* ba = (const float*)d_in[2];   // (12288)
  const float* Wp = (const float*)d_in[3];   // (4096,4096)
  const float* bp = (const float*)d_in[4];   // (4096)
  float* out = (float*)d_out;                // (64,64,4096) fp32

  // workspace layout (ushort elems), regions reused across phases:
  unsigned short* regA = (unsigned short*)d_ws;                 // 33.5 MB
  unsigned short* regB = regA + (size_t)16777216;               // 100.7 MB
  unsigned short* regC = regB + (size_t)50331648;               // 100.7 MB
  unsigned short* xb   = regA;
  unsigned short* Wab  = regB;
  unsigned short* qkvb = regC;
  unsigned short* Wpb  = regA;   // reuse after GEMM1 consumed xb
  unsigned short* yb   = regB;   // reuse after GEMM1 consumed Wab

  cvt_f32_bf16<<<(16777216 / 8) / 256, 256, 0, stream>>>(x, xb, 16777216 / 8);
  cvt_f32_bf16<<<(50331648 / 8) / 256, 256, 0, stream>>>(Wa, Wab, 50331648 / 8);

  // qkv = x @ Wa^T + ba   (M=4096, N=12288, K=4096), bf16 out; grid 16x48=768
  gemm256<1><<<dim3((M_TOK / 256) * (N_QKV / 256)), dim3(512), 0, stream>>>(
      xb, Wab, ba, (void*)qkvb, N_QKV);

  cvt_f32_bf16<<<(16777216 / 8) / 256, 256, 0, stream>>>(Wp, Wpb, 16777216 / 8);

  attn_mfma<<<M_TOK, 64, 0, stream>>>(qkvb, yb);

  // out = y @ Wp^T + bp   (M=4096, N=4096, K=4096), fp32 out; grid 16x16=256
  gemm256<0><<<dim3((M_TOK / 256) * (C_DIM / 256)), dim3(512), 0, stream>>>(
      yb, Wpb, bp, (void*)out, C_DIM);
}

// Round 3
// 950.919 us; speedup vs baseline: 1.1071x; 1.0108x over previous
//
#include <hip/hip_runtime.h>
#include <stdint.h>

// Problem constants: B=64, T=64, C=4096, H=64, hd=64, rank=1, scale=0.125
#define M_TOK   4096      // B*T
#define C_DIM   4096
#define N_QKV   12288
#define KD      4096      // K for both GEMMs
#define NT2     32        // (KD/64)/2 iterations, 2 K-tiles each

typedef __bf16 bf16x8 __attribute__((ext_vector_type(8)));
typedef float  f32x4  __attribute__((ext_vector_type(4)));
typedef unsigned short ushort8 __attribute__((ext_vector_type(8)));

__device__ __forceinline__ unsigned short f2bf(float f) {
  unsigned int u = __builtin_bit_cast(unsigned int, f);
  u = (u + 0x7FFFu + ((u >> 16) & 1u)) >> 16;   // RNE
  return (unsigned short)u;
}

// ---------------- fp32 -> bf16 conversion (16B out per thread) ----------------
__global__ __launch_bounds__(256) void cvt_f32_bf16(const float* __restrict__ in,
                                                    unsigned short* __restrict__ out,
                                                    int n16) {  // n16 = elems/8
  int idx = blockIdx.x * 256 + threadIdx.x;
  if (idx >= n16) return;
  const float4* p = (const float4*)in;
  float4 a = p[idx * 2], b = p[idx * 2 + 1];
  uint4 r;
  r.x = (unsigned)f2bf(a.x) | ((unsigned)f2bf(a.y) << 16);
  r.y = (unsigned)f2bf(a.z) | ((unsigned)f2bf(a.w) << 16);
  r.z = (unsigned)f2bf(b.x) | ((unsigned)f2bf(b.y) << 16);
  r.w = (unsigned)f2bf(b.z) | ((unsigned)f2bf(b.w) << 16);
  ((uint4*)out)[idx] = r;
}

#define GLLDS(gp, lp) \
  __builtin_amdgcn_global_load_lds((const __attribute__((address_space(1))) unsigned int*)(gp), \
                                   (__attribute__((address_space(3))) unsigned int*)(lp), 16, 0, 0)

// =====================================================================
// 256x256 8-phase bf16 NT GEMM (C = A[M,K] * B[N,K]^T + bias), K=4096.
// 512 threads = 8 waves (2M x 4N); per-wave output 128x64; BK=64.
// LDS 128 KiB static, A/B K-tile double buffer. Tile t -> buf[t&1].
//
// vs previous round: (a) NO explicit lgkmcnt(0) before the MFMA cluster —
// ds_reads are compiler-visible loads, so the compiler emits fine-grained
// per-use lgkmcnt(N); reads issued in kk-major consumption order so the
// first 6 reads unlock the first 8 MFMAs while the rest drain under them
// (LDS pipe and MFMA pipe overlap instead of adding). (b) ONE barrier per
// phase (was 2): every read retires before its consuming MFMA, and all
// MFMAs issue before the phase barrier, so the end-barrier alone gives
// the cross-wave read-complete < stage-issue (WAR) ordering. Re-verified:
//   WAR: S0b0 rd P1/st P2; T0b0 rd P1/st P3; T1b0 rd P2/st P4; S1b0 rd P3/
//        st P5; S0b1 rd P5/st P6; T0b1 rd P5/st P7; T1b1 rd P6/st P8;
//        S1b1 rd P7/st next-P1 — all gaps >= 1 barrier.
//   RAW: vmcnt(6) at P4/P8 ends retires exactly through the stages feeding
//        the next 4 phases' reads (3 half-tiles stay in flight, never 0).
// Stage issued at phase START (T3 recipe). Tail stages clamp to tile 63.
// =====================================================================

#define STAGE_A(buf, hf, tau) do {                                         \
    const unsigned short* g_ = Ag + (size_t)((hf) * 64) * KD + (tau) * 64; \
    unsigned short* d_ = As + (buf) * 16384 + (hf) * 8192 + t * 8;         \
    GLLDS(g_, d_);                                                         \
    GLLDS(g_ + (size_t)128 * KD, d_ + 4096);                               \
  } while (0)

#define STAGE_B(buf, nhf, tau) do {                                         \
    const unsigned short* g_ = Bg + (size_t)((nhf) * 32) * KD + (tau) * 64; \
    unsigned short* d_ = Bs + (buf) * 16384 + (nhf) * 8192 + t * 8;         \
    GLLDS(g_, d_);                                                          \
    GLLDS(g_ + (size_t)128 * KD, d_ + 4096);                                \
  } while (0)

// A-frags, kk-major issue order (kk0 block first)
#define LDA_(buf, mh) do {                                                        \
    const unsigned short* pa_ = As + (buf) * 16384 + (mh) * 8192 + wm * 4096 + lr * 64; \
    afk[0][0] = *(const bf16x8*)(pa_ + 0 * 1024 + ck0);                           \
    afk[0][1] = *(const bf16x8*)(pa_ + 1 * 1024 + ck0);                           \
    afk[0][2] = *(const bf16x8*)(pa_ + 2 * 1024 + ck0);                           \
    afk[0][3] = *(const bf16x8*)(pa_ + 3 * 1024 + ck0);                           \
    afk[1][0] = *(const bf16x8*)(pa_ + 0 * 1024 + ck1);                           \
    afk[1][1] = *(const bf16x8*)(pa_ + 1 * 1024 + ck1);                           \
    afk[1][2] = *(const bf16x8*)(pa_ + 2 * 1024 + ck1);                           \
    afk[1][3] = *(const bf16x8*)(pa_ + 3 * 1024 + ck1);                           \
  } while (0)

// B-frags, kk-major
#define LDB_(buf, nhf, dst) do {                                                  \
    const unsigned short* pb_ = Bs + (buf) * 16384 + (nhf) * 8192 + wn * 2048 + lr * 64; \
    dst[0][0] = *(const bf16x8*)(pb_ + 0 * 1024 + ck0);                           \
    dst[0][1] = *(const bf16x8*)(pb_ + 1 * 1024 + ck0);                           \
    dst[1][0] = *(const bf16x8*)(pb_ + 0 * 1024 + ck1);                           \
    dst[1][1] = *(const bf16x8*)(pb_ + 1 * 1024 + ck1);                           \
  } while (0)

// combined A+B frags for P1/P5: issue kk0 group (afk[0][*], b[0][*]) first
// so the kk0 MFMA octet can start after 6 reads while kk1 reads drain.
#define LDAB_(buf, mh, nhf, dst) do {                                             \
    const unsigned short* pa_ = As + (buf) * 16384 + (mh) * 8192 + wm * 4096 + lr * 64; \
    const unsigned short* pb_ = Bs + (buf) * 16384 + (nhf) * 8192 + wn * 2048 + lr * 64; \
    afk[0][0] = *(const bf16x8*)(pa_ + 0 * 1024 + ck0);                           \
    afk[0][1] = *(const bf16x8*)(pa_ + 1 * 1024 + ck0);                           \
    afk[0][2] = *(const bf16x8*)(pa_ + 2 * 1024 + ck0);                           \
    afk[0][3] = *(const bf16x8*)(pa_ + 3 * 1024 + ck0);                           \
    dst[0][0] = *(const bf16x8*)(pb_ + 0 * 1024 + ck0);                           \
    dst[0][1] = *(const bf16x8*)(pb_ + 1 * 1024 + ck0);                           \
    afk[1][0] = *(const bf16x8*)(pa_ + 0 * 1024 + ck1);                           \
    afk[1][1] = *(const bf16x8*)(pa_ + 1 * 1024 + ck1);                           \
    afk[1][2] = *(const bf16x8*)(pa_ + 2 * 1024 + ck1);                           \
    afk[1][3] = *(const bf16x8*)(pa_ + 3 * 1024 + ck1);                           \
    dst[1][0] = *(const bf16x8*)(pb_ + 0 * 1024 + ck1);                           \
    dst[1][1] = *(const bf16x8*)(pb_ + 1 * 1024 + ck1);                           \
  } while (0)

#define QUAD_(mh, nhf, bsrc) do {                                                 \
    __builtin_amdgcn_s_setprio(1);                                                \
    _Pragma("unroll") for (int kk_ = 0; kk_ < 2; ++kk_)                           \
    _Pragma("unroll") for (int mt_ = 0; mt_ < 4; ++mt_)                           \
    _Pragma("unroll") for (int nt_ = 0; nt_ < 2; ++nt_)                           \
      acc[mh][nhf][mt_][nt_] = __builtin_amdgcn_mfma_f32_16x16x32_bf16(           \
          afk[kk_][mt_], bsrc[kk_][nt_], acc[mh][nhf][mt_][nt_], 0, 0, 0);        \
    __builtin_amdgcn_s_setprio(0);                                                \
  } while (0)

#define BAR_() do {                                        \
    asm volatile("" ::: "memory");                         \
    __builtin_amdgcn_s_barrier();                          \
    asm volatile("" ::: "memory");                         \
  } while (0)

// counted vmcnt (T4): 3 half-tiles (6 loads) stay in flight across barrier
#define VM6_() asm volatile("s_waitcnt vmcnt(6)" ::: "memory")

template <int OUT_BF16>
__global__ __launch_bounds__(512, 2) void gemm256(const unsigned short* __restrict__ A,
                                                  const unsigned short* __restrict__ B,
                                                  const float* __restrict__ bias,
                                                  void* __restrict__ Cptr,
                                                  int N) {
  // 128 KiB static LDS (gfx950: 160 KiB/CU) — 1 block/CU, 8 waves
  __shared__ __align__(16) unsigned short As[32768];
  __shared__ __align__(16) unsigned short Bs[32768];

  const int t   = threadIdx.x;
  const int nwg = gridDim.x;
  const int bid = blockIdx.x;
  // T1: bijective XCD swizzle (nwg % 8 == 0 for all our launches)
  const int wg  = (bid & 7) * (nwg >> 3) + (bid >> 3);
  const int bm  = wg & 15;             // M/256 == 16 always; bn-major chunks
  const int bn  = wg >> 4;             // -> per-XCD B-panel reuse in its L2

  const int w  = t >> 6, l = t & 63;
  const int wm = w >> 2, wn = w & 3;   // 2M x 4N wave grid
  const int lr = l & 15, lq = l >> 4;
  const int ck0 = (lq ^ (lr & 7)) * 8; // un-swizzled read chunk, kk=0
  const int ck1 = ck0 ^ 32;            // kk=1 (chunk ^ 4 -> elems ^ 32)

  // staging thread-constants: thread t covers row r8=t>>3, source chunk
  // pre-swizzled so LDS(row,c) = global chunk c^(row&7)  [G21: both sides]
  const int r8  = t >> 3;
  const int kcs = ((t & 7) ^ (r8 & 7)) * 8;
  const unsigned short* Ag = A + (size_t)(bm * 256 + r8) * KD + kcs;
  const unsigned short* Bg = B + (size_t)(bn * 256 + ((t >> 8) << 6) + (r8 & 31)) * KD + kcs;

  f32x4 acc[2][2][4][2] = {};          // [mh][nhf][mt][nt] = 128 acc regs
  bf16x8 afk[2][4], bA[2][2], bB[2][2];

  // prologue: tile0 {S0,T0,T1,S1}, tile1 {S0,T0,T1}; tile0 landed, 3 in flight
  STAGE_A(0, 0, 0); STAGE_B(0, 0, 0); STAGE_B(0, 1, 0); STAGE_A(0, 1, 0);
  STAGE_A(1, 0, 1); STAGE_B(1, 0, 1); STAGE_B(1, 1, 1);
  VM6_();
  BAR_();

#pragma unroll 1
  for (int i = 0; i < NT2; ++i) {
    const int t1 = 2 * i + 1;
    const int t2 = (2 * i + 2 < 64) ? 2 * i + 2 : 63;   // clamp: dead stages
    const int t3 = (2 * i + 3 < 64) ? 2 * i + 3 : 63;
    // P1
    STAGE_A(1, 1, t1);
    LDAB_(0, 0, 0, bA);
    QUAD_(0, 0, bA);
    BAR_();
    // P2
    STAGE_A(0, 0, t2);
    LDB_(0, 1, bB);
    QUAD_(0, 1, bB);
    BAR_();
    // P3
    STAGE_B(0, 0, t2);
    LDA_(0, 1);
    QUAD_(1, 0, bA);
    BAR_();
    // P4
    STAGE_B(0, 1, t2);
    QUAD_(1, 1, bB);
    VM6_();
    BAR_();
    // P5
    STAGE_A(0, 1, t2);
    LDAB_(1, 0, 0, bA);
    QUAD_(0, 0, bA);
    BAR_();
    // P6
    STAGE_A(1, 0, t3);
    LDB_(1, 1, bB);
    QUAD_(0, 1, bB);
    BAR_();
    // P7
    STAGE_B(1, 0, t3);
    LDA_(1, 1);
    QUAD_(1, 0, bA);
    BAR_();
    // P8
    STAGE_B(1, 1, t3);
    QUAD_(1, 1, bB);
    VM6_();
    BAR_();
  }

  // drain the 6 in-flight LDS-DMA loads before waves can exit
  asm volatile("s_waitcnt vmcnt(0)" ::: "memory");

  // epilogue: C/D layout col=lane&15, row=(lane>>4)*4+reg
  const int row0 = bm * 256 + wm * 128 + lq * 4;
  const int col0 = bn * 256 + wn * 64 + lr;
#pragma unroll
  for (int nhf = 0; nhf < 2; ++nhf)
#pragma unroll
    for (int nt = 0; nt < 2; ++nt) {
      const int col = col0 + nhf * 32 + nt * 16;
      const float bv = bias[col];
#pragma unroll
      for (int mh = 0; mh < 2; ++mh)
#pragma unroll
        for (int mt = 0; mt < 4; ++mt) {
          const int row = row0 + mh * 64 + mt * 16;
#pragma unroll
          for (int rg = 0; rg < 4; ++rg) {
            float v = acc[mh][nhf][mt][nt][rg] + bv;
            if (OUT_BF16)
              ((unsigned short*)Cptr)[(size_t)(row + rg) * N + col] = f2bf(v);
            else
              ((float*)Cptr)[(size_t)(row + rg) * N + col] = v;
          }
        }
    }
}

// ---------------- head-mixing attention, MFMA, one WAVE per (b,t) -------------
// (unchanged — not the bottleneck this round)
#define AST 72   // padded LDS row stride (elements)

__global__ __launch_bounds__(64) void attn_mfma(const unsigned short* __restrict__ qkv,
                                                unsigned short* __restrict__ y) {
  __shared__ __align__(16) unsigned short Ks[64 * AST];   // K, later P
  __shared__ __align__(16) unsigned short Vs[64 * AST];
  const int l  = threadIdx.x;
  const int lr = l & 15;
  const int lq = l >> 4;
  const size_t base = (size_t)blockIdx.x * 12288;

  // ---- stage K,V (coalesced 16B loads, padded LDS rows) ----
  {
    const int jr = l >> 3;          // 0..7
    const int cc = (l & 7) * 8;     // col chunk (elements)
#pragma unroll
    for (int c = 0; c < 8; ++c) {
      const int j = c * 8 + jr;
      *(uint4*)(Ks + j * AST + cc) = *(const uint4*)(qkv + base + 4096 + (size_t)j * 64 + cc);
      *(uint4*)(Vs + j * AST + cc) = *(const uint4*)(qkv + base + 8192 + (size_t)j * 64 + cc);
    }
  }

  // ---- Q A-frags direct from global ----
  bf16x8 aq[4][2];
#pragma unroll
  for (int it = 0; it < 4; ++it)
#pragma unroll
    for (int kk = 0; kk < 2; ++kk)
      aq[it][kk] = *(const bf16x8*)(qkv + base + (size_t)(it * 16 + lr) * 64 + kk * 32 + lq * 8);

  __syncthreads();

  // ---- S = Q K^T ----
  f32x4 acc[4][4] = {};
#pragma unroll
  for (int kk = 0; kk < 2; ++kk) {
    bf16x8 bk[4];
#pragma unroll
    for (int jt = 0; jt < 4; ++jt)
      bk[jt] = *(const bf16x8*)(Ks + (jt * 16 + lr) * AST + kk * 32 + lq * 8);
#pragma unroll
    for (int it = 0; it < 4; ++it)
#pragma unroll
      for (int jt = 0; jt < 4; ++jt)
        acc[it][jt] = __builtin_amdgcn_mfma_f32_16x16x32_bf16(aq[it][kk], bk[jt], acc[it][jt], 0, 0, 0);
  }

  // ---- mask + softmax in-register ----
#pragma unroll
  for (int it = 0; it < 4; ++it) {
#pragma unroll
    for (int rg = 0; rg < 4; ++rg) {
      const int row = it * 16 + lq * 4 + rg;
      float mx = -1e30f;
#pragma unroll
      for (int jt = 0; jt < 4; ++jt) {
        const int col = jt * 16 + lr;
        float s = acc[it][jt][rg] * 0.125f;
        s = (col <= row) ? s : -1e30f;
        acc[it][jt][rg] = s;
        mx = fmaxf(mx, s);
      }
#pragma unroll
      for (int d = 1; d < 16; d <<= 1)
        mx = fmaxf(mx, __shfl_xor(mx, d));
      float sum = 0.f;
#pragma unroll
      for (int jt = 0; jt < 4; ++jt) {
        float e = __expf(acc[it][jt][rg] - mx);
        acc[it][jt][rg] = e;
        sum += e;
      }
#pragma unroll
      for (int d = 1; d < 16; d <<= 1)
        sum += __shfl_xor(sum, d);
      const float inv = 1.f / sum;
#pragma unroll
      for (int jt = 0; jt < 4; ++jt)
        acc[it][jt][rg] *= inv;
    }
  }

  // ---- P -> LDS (bf16), reusing K slab ----
#pragma unroll
  for (int it = 0; it < 4; ++it)
#pragma unroll
    for (int rg = 0; rg < 4; ++rg) {
      const int row = it * 16 + lq * 4 + rg;
#pragma unroll
      for (int jt = 0; jt < 4; ++jt)
        Ks[row * AST + jt * 16 + lr] = f2bf(acc[it][jt][rg]);
    }
  __syncthreads();

  // ---- Y = P V ----
  f32x4 out[4][4] = {};
#pragma unroll
  for (int kk = 0; kk < 2; ++kk) {
    bf16x8 ap[4];
#pragma unroll
    for (int it = 0; it < 4; ++it)
      ap[it] = *(const bf16x8*)(Ks + (it * 16 + lr) * AST + kk * 32 + lq * 8);
#pragma unroll
    for (int dt = 0; dt < 4; ++dt) {
      ushort8 vt;
#pragma unroll
      for (int jj = 0; jj < 8; ++jj)
        vt[jj] = Vs[(kk * 32 + lq * 8 + jj) * AST + dt * 16 + lr];
      const bf16x8 bv = __builtin_bit_cast(bf16x8, vt);
#pragma unroll
      for (int it = 0; it < 4; ++it)
        out[it][dt] = __builtin_amdgcn_mfma_f32_16x16x32_bf16(ap[it], bv, out[it][dt], 0, 0, 0);
    }
  }

  // ---- epilogue: y[bt][i*64+d] bf16 ----
  unsigned short* yrow = y + (size_t)blockIdx.x * 4096;
#pragma unroll
  for (int it = 0; it < 4; ++it)
#pragma unroll
    for (int rg = 0; rg < 4; ++rg) {
      const int i = it * 16 + lq * 4 + rg;
#pragma unroll
      for (int dt = 0; dt < 4; ++dt)
        yrow[i * 64 + dt * 16 + lr] = f2bf(out[it][dt][rg]);
    }
}

// ---------------- launch ------------------------------------------------------
extern "C" void kernel_launch(void* const* d_in, const int* in_sizes, int n_in,
                              void* d_out, int out_size, void* d_ws, size_t ws_size,
                              hipStream_t stream) {
  const float* x  = (const float*)d_in[0];   // (64,64,4096)
  const float* Wa = (const float*)d_in[1];   // (12288,4096)
  const float* ba = (const float*)d_in[2];   // (12288)
  const float* Wp = (const float*)d_in[3];   // (4096,4096)
  const float* bp = (const float*)d_in[4];   // (4096)
  float* out = (float*)d_out;                // (64,64,4096) fp32

  // workspace layout (ushort elems), regions reused across phases:
  unsigned short* regA = (unsigned short*)d_ws;                 // 33.5 MB
  unsigned short* regB = regA + (size_t)16777216;               // 100.7 MB
  unsigned short* regC = regB + (size_t)50331648;               // 100.7 MB
  unsigned short* xb   = regA;
  unsigned short* Wab  = regB;
  unsigned short* qkvb = regC;
  unsigned short* Wpb  = regA;   // reuse after GEMM1 consumed xb
  unsigned short* yb   = regB;   // reuse after GEMM1 consumed Wab

  cvt_f32_bf16<<<(16777216 / 8) / 256, 256, 0, stream>>>(x, xb, 16777216 / 8);
  cvt_f32_bf16<<<(50331648 / 8) / 256, 256, 0, stream>>>(Wa, Wab, 50331648 / 8);

  // qkv = x @ Wa^T + ba   (M=4096, N=12288, K=4096), bf16 out; grid 768
  gemm256<1><<<dim3((M_TOK / 256) * (N_QKV / 256)), dim3(512), 0, stream>>>(
      xb, Wab, ba, (void*)qkvb, N_QKV);

  cvt_f32_bf16<<<(16777216 / 8) / 256, 256, 0, stream>>>(Wp, Wpb, 16777216 / 8);

  attn_mfma<<<M_TOK, 64, 0, stream>>>(qkvb, yb);

  // out = y @ Wp^T + bp   (M=4096, N=4096, K=4096), fp32 out; grid 256
  gemm256<0><<<dim3((M_TOK / 256) * (C_DIM / 256)), dim3(512), 0, stream>>>(
      yb, Wpb, bp, (void*)out, C_DIM);
}

// Round 4
// 944.518 us; speedup vs baseline: 1.1146x; 1.0068x over previous
//
#include <hip/hip_runtime.h>
#include <stdint.h>

// Problem constants: B=64, T=64, C=4096, H=64, hd=64, rank=1, scale=0.125
#define M_TOK   4096      // B*T
#define C_DIM   4096
#define N_QKV   12288
#define KD      4096      // K for both GEMMs
#define NT2     32        // (KD/64)/2 iterations, 2 K-tiles each

typedef __bf16 bf16x8 __attribute__((ext_vector_type(8)));
typedef float  f32x4  __attribute__((ext_vector_type(4)));
typedef unsigned short ushort8 __attribute__((ext_vector_type(8)));

__device__ __forceinline__ unsigned short f2bf(float f) {
  unsigned int u = __builtin_bit_cast(unsigned int, f);
  u = (u + 0x7FFFu + ((u >> 16) & 1u)) >> 16;   // RNE
  return (unsigned short)u;
}

// ---------------- fp32 -> bf16 conversion (16B out per thread) ----------------
__global__ __launch_bounds__(256) void cvt_f32_bf16(const float* __restrict__ in,
                                                    unsigned short* __restrict__ out,
                                                    int n16) {  // n16 = elems/8
  int idx = blockIdx.x * 256 + threadIdx.x;
  if (idx >= n16) return;
  const float4* p = (const float4*)in;
  float4 a = p[idx * 2], b = p[idx * 2 + 1];
  uint4 r;
  r.x = (unsigned)f2bf(a.x) | ((unsigned)f2bf(a.y) << 16);
  r.y = (unsigned)f2bf(a.z) | ((unsigned)f2bf(a.w) << 16);
  r.z = (unsigned)f2bf(b.x) | ((unsigned)f2bf(b.y) << 16);
  r.w = (unsigned)f2bf(b.z) | ((unsigned)f2bf(b.w) << 16);
  ((uint4*)out)[idx] = r;
}

#define GLLDS(gp, lp) \
  __builtin_amdgcn_global_load_lds((const __attribute__((address_space(1))) unsigned int*)(gp), \
                                   (__attribute__((address_space(3))) unsigned int*)(lp), 16, 0, 0)

// =====================================================================
// 256x256 bf16 NT GEMM (C = A[M,K] * B[N,K]^T + bias), K=4096.
// 512 threads = 8 waves (2M x 4N); per-wave output 128x64; BK=64.
// LDS 128 KiB static, A/B K-tile double buffer. Tile t -> buf[t&1].
//
// FREE-RUNNING TILE SCHEDULE (this round's change): ONE barrier per K-tile
// (was 4 per tile). Rounds 2-3 showed 39-40% MfmaUtil with per-phase
// barriers: waves in lockstep -> everyone reads (LDS saturated, MFMA idle)
// then everyone MFMAs (matrix busy, LDS idle); pipes ADD (~11k cyc/iter)
// instead of overlap (LDS ~3.1k + MFMA ~4.1k cyc/iter/CU demands).
// Now per tile: issue 4 half-tile stages for tile t+1 into buf^1, then run
// 4 quadrant groups (ds_reads -> MFMAs, fine-grained compiler lgkmcnt) with
// no intra-tile barriers. Waves desync via pipe arbitration -> one wave's
// read drain overlaps another's MFMA cluster (what setprio arbitrates, T5).
// Hazards:
//   WAR: stage(t+1 -> buf^1) issues after the tile-(t-1) end barrier; all
//        reads of buf^1 retired before that barrier (each read's consuming
//        MFMA issued before it, which implies the read completed). SAFE.
//   RAW: vmcnt(0) at tile end waits for the 8 stages issued one full tile
//        of compute (~2000 cyc) earlier -> ~free; barrier then releases
//        the next tile's reads. Lookahead depth 1, so vmcnt(0) is exact.
// Tail: last odd tile stages tile 63 again into buf0 (dead, in-bounds).
// =====================================================================

#define STAGE_A(buf, hf, tau) do {                                         \
    const unsigned short* g_ = Ag + (size_t)((hf) * 64) * KD + (tau) * 64; \
    unsigned short* d_ = As + (buf) * 16384 + (hf) * 8192 + t * 8;         \
    GLLDS(g_, d_);                                                         \
    GLLDS(g_ + (size_t)128 * KD, d_ + 4096);                               \
  } while (0)

#define STAGE_B(buf, nhf, tau) do {                                         \
    const unsigned short* g_ = Bg + (size_t)((nhf) * 32) * KD + (tau) * 64; \
    unsigned short* d_ = Bs + (buf) * 16384 + (nhf) * 8192 + t * 8;         \
    GLLDS(g_, d_);                                                          \
    GLLDS(g_ + (size_t)128 * KD, d_ + 4096);                                \
  } while (0)

// A-frags, kk-major issue order (kk0 block first)
#define LDA_(buf, mh) do {                                                        \
    const unsigned short* pa_ = As + (buf) * 16384 + (mh) * 8192 + wm * 4096 + lr * 64; \
    afk[0][0] = *(const bf16x8*)(pa_ + 0 * 1024 + ck0);                           \
    afk[0][1] = *(const bf16x8*)(pa_ + 1 * 1024 + ck0);                           \
    afk[0][2] = *(const bf16x8*)(pa_ + 2 * 1024 + ck0);                           \
    afk[0][3] = *(const bf16x8*)(pa_ + 3 * 1024 + ck0);                           \
    afk[1][0] = *(const bf16x8*)(pa_ + 0 * 1024 + ck1);                           \
    afk[1][1] = *(const bf16x8*)(pa_ + 1 * 1024 + ck1);                           \
    afk[1][2] = *(const bf16x8*)(pa_ + 2 * 1024 + ck1);                           \
    afk[1][3] = *(const bf16x8*)(pa_ + 3 * 1024 + ck1);                           \
  } while (0)

// B-frags, kk-major
#define LDB_(buf, nhf, dst) do {                                                  \
    const unsigned short* pb_ = Bs + (buf) * 16384 + (nhf) * 8192 + wn * 2048 + lr * 64; \
    dst[0][0] = *(const bf16x8*)(pb_ + 0 * 1024 + ck0);                           \
    dst[0][1] = *(const bf16x8*)(pb_ + 1 * 1024 + ck0);                           \
    dst[1][0] = *(const bf16x8*)(pb_ + 0 * 1024 + ck1);                           \
    dst[1][1] = *(const bf16x8*)(pb_ + 1 * 1024 + ck1);                           \
  } while (0)

// combined A+B frags: kk0 group first so the kk0 MFMA octet can start
// after 6 reads while kk1 reads drain.
#define LDAB_(buf, mh, nhf, dst) do {                                             \
    const unsigned short* pa_ = As + (buf) * 16384 + (mh) * 8192 + wm * 4096 + lr * 64; \
    const unsigned short* pb_ = Bs + (buf) * 16384 + (nhf) * 8192 + wn * 2048 + lr * 64; \
    afk[0][0] = *(const bf16x8*)(pa_ + 0 * 1024 + ck0);                           \
    afk[0][1] = *(const bf16x8*)(pa_ + 1 * 1024 + ck0);                           \
    afk[0][2] = *(const bf16x8*)(pa_ + 2 * 1024 + ck0);                           \
    afk[0][3] = *(const bf16x8*)(pa_ + 3 * 1024 + ck0);                           \
    dst[0][0] = *(const bf16x8*)(pb_ + 0 * 1024 + ck0);                           \
    dst[0][1] = *(const bf16x8*)(pb_ + 1 * 1024 + ck0);                           \
    afk[1][0] = *(const bf16x8*)(pa_ + 0 * 1024 + ck1);                           \
    afk[1][1] = *(const bf16x8*)(pa_ + 1 * 1024 + ck1);                           \
    afk[1][2] = *(const bf16x8*)(pa_ + 2 * 1024 + ck1);                           \
    afk[1][3] = *(const bf16x8*)(pa_ + 3 * 1024 + ck1);                           \
    dst[1][0] = *(const bf16x8*)(pb_ + 0 * 1024 + ck1);                           \
    dst[1][1] = *(const bf16x8*)(pb_ + 1 * 1024 + ck1);                           \
  } while (0)

#define QUAD_(mh, nhf, bsrc) do {                                                 \
    __builtin_amdgcn_s_setprio(1);                                                \
    _Pragma("unroll") for (int kk_ = 0; kk_ < 2; ++kk_)                           \
    _Pragma("unroll") for (int mt_ = 0; mt_ < 4; ++mt_)                           \
    _Pragma("unroll") for (int nt_ = 0; nt_ < 2; ++nt_)                           \
      acc[mh][nhf][mt_][nt_] = __builtin_amdgcn_mfma_f32_16x16x32_bf16(           \
          afk[kk_][mt_], bsrc[kk_][nt_], acc[mh][nhf][mt_][nt_], 0, 0, 0);        \
    __builtin_amdgcn_s_setprio(0);                                                \
  } while (0)

#define BAR_() do {                                        \
    asm volatile("" ::: "memory");                         \
    __builtin_amdgcn_s_barrier();                          \
    asm volatile("" ::: "memory");                         \
  } while (0)

#define VM0_() asm volatile("s_waitcnt vmcnt(0)" ::: "memory")

template <int OUT_BF16>
__global__ __launch_bounds__(512, 2) void gemm256(const unsigned short* __restrict__ A,
                                                  const unsigned short* __restrict__ B,
                                                  const float* __restrict__ bias,
                                                  void* __restrict__ Cptr,
                                                  int N) {
  // 128 KiB static LDS (gfx950: 160 KiB/CU) — 1 block/CU, 8 waves
  __shared__ __align__(16) unsigned short As[32768];
  __shared__ __align__(16) unsigned short Bs[32768];

  const int t   = threadIdx.x;
  const int nwg = gridDim.x;
  const int bid = blockIdx.x;
  // T1: bijective XCD swizzle (nwg % 8 == 0 for all our launches)
  const int wg  = (bid & 7) * (nwg >> 3) + (bid >> 3);
  const int bm  = wg & 15;             // M/256 == 16 always; bn-major chunks
  const int bn  = wg >> 4;             // -> per-XCD B-panel reuse in its L2

  const int w  = t >> 6, l = t & 63;
  const int wm = w >> 2, wn = w & 3;   // 2M x 4N wave grid
  const int lr = l & 15, lq = l >> 4;
  const int ck0 = (lq ^ (lr & 7)) * 8; // un-swizzled read chunk, kk=0
  const int ck1 = ck0 ^ 32;            // kk=1 (chunk ^ 4 -> elems ^ 32)

  // staging thread-constants: thread t covers row r8=t>>3, source chunk
  // pre-swizzled so LDS(row,c) = global chunk c^(row&7)  [G21: both sides]
  const int r8  = t >> 3;
  const int kcs = ((t & 7) ^ (r8 & 7)) * 8;
  const unsigned short* Ag = A + (size_t)(bm * 256 + r8) * KD + kcs;
  const unsigned short* Bg = B + (size_t)(bn * 256 + ((t >> 8) << 6) + (r8 & 31)) * KD + kcs;

  f32x4 acc[2][2][4][2] = {};          // [mh][nhf][mt][nt] = 128 acc regs
  bf16x8 afk[2][4], bA[2][2], bB[2][2];

  // prologue: stage tile 0 into buf0 (4 halves), drain, sync
  STAGE_A(0, 0, 0); STAGE_A(0, 1, 0); STAGE_B(0, 0, 0); STAGE_B(0, 1, 0);
  VM0_();
  BAR_();

#pragma unroll 1
  for (int i = 0; i < NT2; ++i) {
    const int t1 = 2 * i + 1;                           // <= 63 always
    const int t2 = (2 * i + 2 < 64) ? 2 * i + 2 : 63;   // clamp: dead stage

    // ---- even tile 2i (buf0); prefetch tile 2i+1 -> buf1 ----
    STAGE_A(1, 0, t1); STAGE_A(1, 1, t1); STAGE_B(1, 0, t1); STAGE_B(1, 1, t1);
    LDAB_(0, 0, 0, bA); QUAD_(0, 0, bA);
    LDB_(0, 1, bB);     QUAD_(0, 1, bB);
    LDA_(0, 1);         QUAD_(1, 0, bA);
                        QUAD_(1, 1, bB);
    VM0_();   // tile 2i+1 staged (issued ~full tile of compute ago)
    BAR_();

    // ---- odd tile 2i+1 (buf1); prefetch tile 2i+2 -> buf0 ----
    STAGE_A(0, 0, t2); STAGE_A(0, 1, t2); STAGE_B(0, 0, t2); STAGE_B(0, 1, t2);
    LDAB_(1, 0, 0, bA); QUAD_(0, 0, bA);
    LDB_(1, 1, bB);     QUAD_(0, 1, bB);
    LDA_(1, 1);         QUAD_(1, 0, bA);
                        QUAD_(1, 1, bB);
    VM0_();
    BAR_();
  }

  // epilogue: C/D layout col=lane&15, row=(lane>>4)*4+reg
  const int row0 = bm * 256 + wm * 128 + lq * 4;
  const int col0 = bn * 256 + wn * 64 + lr;
#pragma unroll
  for (int nhf = 0; nhf < 2; ++nhf)
#pragma unroll
    for (int nt = 0; nt < 2; ++nt) {
      const int col = col0 + nhf * 32 + nt * 16;
      const float bv = bias[col];
#pragma unroll
      for (int mh = 0; mh < 2; ++mh)
#pragma unroll
        for (int mt = 0; mt < 4; ++mt) {
          const int row = row0 + mh * 64 + mt * 16;
#pragma unroll
          for (int rg = 0; rg < 4; ++rg) {
            float v = acc[mh][nhf][mt][nt][rg] + bv;
            if (OUT_BF16)
              ((unsigned short*)Cptr)[(size_t)(row + rg) * N + col] = f2bf(v);
            else
              ((float*)Cptr)[(size_t)(row + rg) * N + col] = v;
          }
        }
    }
}

// ---------------- head-mixing attention, MFMA, one WAVE per (b,t) -------------
// (unchanged — will read its counters once GEMMs drop out of the top-5)
#define AST 72   // padded LDS row stride (elements)

__global__ __launch_bounds__(64) void attn_mfma(const unsigned short* __restrict__ qkv,
                                                unsigned short* __restrict__ y) {
  __shared__ __align__(16) unsigned short Ks[64 * AST];   // K, later P
  __shared__ __align__(16) unsigned short Vs[64 * AST];
  const int l  = threadIdx.x;
  const int lr = l & 15;
  const int lq = l >> 4;
  const size_t base = (size_t)blockIdx.x * 12288;

  // ---- stage K,V (coalesced 16B loads, padded LDS rows) ----
  {
    const int jr = l >> 3;          // 0..7
    const int cc = (l & 7) * 8;     // col chunk (elements)
#pragma unroll
    for (int c = 0; c < 8; ++c) {
      const int j = c * 8 + jr;
      *(uint4*)(Ks + j * AST + cc) = *(const uint4*)(qkv + base + 4096 + (size_t)j * 64 + cc);
      *(uint4*)(Vs + j * AST + cc) = *(const uint4*)(qkv + base + 8192 + (size_t)j * 64 + cc);
    }
  }

  // ---- Q A-frags direct from global ----
  bf16x8 aq[4][2];
#pragma unroll
  for (int it = 0; it < 4; ++it)
#pragma unroll
    for (int kk = 0; kk < 2; ++kk)
      aq[it][kk] = *(const bf16x8*)(qkv + base + (size_t)(it * 16 + lr) * 64 + kk * 32 + lq * 8);

  __syncthreads();

  // ---- S = Q K^T ----
  f32x4 acc[4][4] = {};
#pragma unroll
  for (int kk = 0; kk < 2; ++kk) {
    bf16x8 bk[4];
#pragma unroll
    for (int jt = 0; jt < 4; ++jt)
      bk[jt] = *(const bf16x8*)(Ks + (jt * 16 + lr) * AST + kk * 32 + lq * 8);
#pragma unroll
    for (int it = 0; it < 4; ++it)
#pragma unroll
      for (int jt = 0; jt < 4; ++jt)
        acc[it][jt] = __builtin_amdgcn_mfma_f32_16x16x32_bf16(aq[it][kk], bk[jt], acc[it][jt], 0, 0, 0);
  }

  // ---- mask + softmax in-register ----
#pragma unroll
  for (int it = 0; it < 4; ++it) {
#pragma unroll
    for (int rg = 0; rg < 4; ++rg) {
      const int row = it * 16 + lq * 4 + rg;
      float mx = -1e30f;
#pragma unroll
      for (int jt = 0; jt < 4; ++jt) {
        const int col = jt * 16 + lr;
        float s = acc[it][jt][rg] * 0.125f;
        s = (col <= row) ? s : -1e30f;
        acc[it][jt][rg] = s;
        mx = fmaxf(mx, s);
      }
#pragma unroll
      for (int d = 1; d < 16; d <<= 1)
        mx = fmaxf(mx, __shfl_xor(mx, d));
      float sum = 0.f;
#pragma unroll
      for (int jt = 0; jt < 4; ++jt) {
        float e = __expf(acc[it][jt][rg] - mx);
        acc[it][jt][rg] = e;
        sum += e;
      }
#pragma unroll
      for (int d = 1; d < 16; d <<= 1)
        sum += __shfl_xor(sum, d);
      const float inv = 1.f / sum;
#pragma unroll
      for (int jt = 0; jt < 4; ++jt)
        acc[it][jt][rg] *= inv;
    }
  }

  // ---- P -> LDS (bf16), reusing K slab ----
#pragma unroll
  for (int it = 0; it < 4; ++it)
#pragma unroll
    for (int rg = 0; rg < 4; ++rg) {
      const int row = it * 16 + lq * 4 + rg;
#pragma unroll
      for (int jt = 0; jt < 4; ++jt)
        Ks[row * AST + jt * 16 + lr] = f2bf(acc[it][jt][rg]);
    }
  __syncthreads();

  // ---- Y = P V ----
  f32x4 out[4][4] = {};
#pragma unroll
  for (int kk = 0; kk < 2; ++kk) {
    bf16x8 ap[4];
#pragma unroll
    for (int it = 0; it < 4; ++it)
      ap[it] = *(const bf16x8*)(Ks + (it * 16 + lr) * AST + kk * 32 + lq * 8);
#pragma unroll
    for (int dt = 0; dt < 4; ++dt) {
      ushort8 vt;
#pragma unroll
      for (int jj = 0; jj < 8; ++jj)
        vt[jj] = Vs[(kk * 32 + lq * 8 + jj) * AST + dt * 16 + lr];
      const bf16x8 bv = __builtin_bit_cast(bf16x8, vt);
#pragma unroll
      for (int it = 0; it < 4; ++it)
        out[it][dt] = __builtin_amdgcn_mfma_f32_16x16x32_bf16(ap[it], bv, out[it][dt], 0, 0, 0);
    }
  }

  // ---- epilogue: y[bt][i*64+d] bf16 ----
  unsigned short* yrow = y + (size_t)blockIdx.x * 4096;
#pragma unroll
  for (int it = 0; it < 4; ++it)
#pragma unroll
    for (int rg = 0; rg < 4; ++rg) {
      const int i = it * 16 + lq * 4 + rg;
#pragma unroll
      for (int dt = 0; dt < 4; ++dt)
        yrow[i * 64 + dt * 16 + lr] = f2bf(out[it][dt][rg]);
    }
}

// ---------------- launch ------------------------------------------------------
extern "C" void kernel_launch(void* const* d_in, const int* in_sizes, int n_in,
                              void* d_out, int out_size, void* d_ws, size_t ws_size,
                              hipStream_t stream) {
  const float* x  = (const float*)d_in[0];   // (64,64,4096)
  const float* Wa = (const float*)d_in[1];   // (12288,4096)
  const float* ba = (const float*)d_in[2];   // (12288)
  const float* Wp = (const float*)d_in[3];   // (4096,4096)
  const float* bp = (const float*)d_in[4];   // (4096)
  float* out = (float*)d_out;                // (64,64,4096) fp32

  // workspace layout (ushort elems), regions reused across phases:
  unsigned short* regA = (unsigned short*)d_ws;                 // 33.5 MB
  unsigned short* regB = regA + (size_t)16777216;               // 100.7 MB
  unsigned short* regC = regB + (size_t)50331648;               // 100.7 MB
  unsigned short* xb   = regA;
  unsigned short* Wab  = regB;
  unsigned short* qkvb = regC;
  unsigned short* Wpb  = regA;   // reuse after GEMM1 consumed xb
  unsigned short* yb   = regB;   // reuse after GEMM1 consumed Wab

  cvt_f32_bf16<<<(16777216 / 8) / 256, 256, 0, stream>>>(x, xb, 16777216 / 8);
  cvt_f32_bf16<<<(50331648 / 8) / 256, 256, 0, stream>>>(Wa, Wab, 50331648 / 8);

  // qkv = x @ Wa^T + ba   (M=4096, N=12288, K=4096), bf16 out; grid 768
  gemm256<1><<<dim3((M_TOK / 256) * (N_QKV / 256)), dim3(512), 0, stream>>>(
      xb, Wab, ba, (void*)qkvb, N_QKV);

  cvt_f32_bf16<<<(16777216 / 8) / 256, 256, 0, stream>>>(Wp, Wpb, 16777216 / 8);

  attn_mfma<<<M_TOK, 64, 0, stream>>>(qkvb, yb);

  // out = y @ Wp^T + bp   (M=4096, N=4096, K=4096), fp32 out; grid 256
  gemm256<0><<<dim3((M_TOK / 256) * (C_DIM / 256)), dim3(512), 0, stream>>>(
      yb, Wpb, bp, (void*)out, C_DIM);
}

// Round 5
// 884.643 us; speedup vs baseline: 1.1901x; 1.0677x over previous
//
#include <hip/hip_runtime.h>
#include <stdint.h>

// Problem constants: B=64, T=64, C=4096, H=64, hd=64, rank=1, scale=0.125
#define M_TOK   4096      // B*T
#define C_DIM   4096
#define N_QKV   12288
#define KD      4096      // K for both GEMMs
#define NT2     32        // (KD/64)/2 iterations, 2 K-tiles each

typedef __bf16 bf16x8 __attribute__((ext_vector_type(8)));
typedef float  f32x4  __attribute__((ext_vector_type(4)));
typedef unsigned short ushort8 __attribute__((ext_vector_type(8)));

__device__ __forceinline__ unsigned short f2bf(float f) {
  unsigned int u = __builtin_bit_cast(unsigned int, f);
  u = (u + 0x7FFFu + ((u >> 16) & 1u)) >> 16;   // RNE
  return (unsigned short)u;
}

// ---------------- fp32 -> bf16 conversion (16B out per thread) ----------------
__global__ __launch_bounds__(256) void cvt_f32_bf16(const float* __restrict__ in,
                                                    unsigned short* __restrict__ out,
                                                    int n16) {  // n16 = elems/8
  int idx = blockIdx.x * 256 + threadIdx.x;
  if (idx >= n16) return;
  const float4* p = (const float4*)in;
  float4 a = p[idx * 2], b = p[idx * 2 + 1];
  uint4 r;
  r.x = (unsigned)f2bf(a.x) | ((unsigned)f2bf(a.y) << 16);
  r.y = (unsigned)f2bf(a.z) | ((unsigned)f2bf(a.w) << 16);
  r.z = (unsigned)f2bf(b.x) | ((unsigned)f2bf(b.y) << 16);
  r.w = (unsigned)f2bf(b.z) | ((unsigned)f2bf(b.w) << 16);
  ((uint4*)out)[idx] = r;
}

#define GLLDS(gp, lp) \
  __builtin_amdgcn_global_load_lds((const __attribute__((address_space(1))) unsigned int*)(gp), \
                                   (__attribute__((address_space(3))) unsigned int*)(lp), 16, 0, 0)

// =====================================================================
// 256x256 bf16 NT GEMM, K=4096. 512 thr = 8 waves (2M x 4N), BK=64,
// LDS 128 KiB double buffer. Tile t -> buf[t&1].
//
// R2-R4 post-mortem: three schedules all = 5630 cyc/tile = exact serial
// sum of MFMA(2484) + LDS reads(2304) + DMA writes(512) + barriers.
// Compiler normalizes unpinned source into read-burst -> MFMA-burst.
// THIS ROUND: register one-phase-lookahead + pinned interleave.
//   - two A-frag banks (afk0=mh0, afk1=mh1) + two B banks (bA=nhf0, bB=nhf1)
//   - quad order per tile: Q00, Q01, Q11, Q10
//   - P1: rd A0,B0 (12; hidden under prev P8 MFMA drain)   MFMA Q00
//     P2: rd B1,A1 (12; Q01 waits lgkmcnt(8)=B1 only)      MFMA Q01
//     P3: rd none  (afk1 drained under Q01)                MFMA Q11
//     P4: rd none                                          MFMA Q10
//   - sched_barrier(0) fences pin read-groups and MFMA clusters so the
//     compiler cannot re-lump (rule #18/#19); 2 s_barriers per phase.
// Stage map + vmcnt(6) IDENTICAL to the verified R2 map:
//   P1:S1(2i+1) P2:S0(2i+2) P3:T0(2i+2) P4:T1(2i+2)+vm6
//   P5:S1(2i+2) P6:S0(2i+3) P7:T0(2i+3) P8:T1(2i+3)+vm6
// WAR: every overwritten half's reads retire >=1 barrier before its stage
//   (S0b0 rd P1/st P2; T0b0 rd P1/st P3; T1b0 rd P2/st P4; S1b0 rd P2/st P5;
//    S0b1 rd P5/st P6; T0b1 rd P5/st P7; T1b1 rd P6/st P8; S1b1 rd P6/st nP1).
// RAW: P4 vmcnt(6) retires all 4 halves of tile 2i+1 (read P5-P6);
//      P8 vmcnt(6) retires all 4 halves of tile 2i+2 (read next P1-P2).
// =====================================================================

#define STAGE_A(buf, hf, tau) do {                                         \
    const unsigned short* g_ = Ag + (size_t)((hf) * 64) * KD + (tau) * 64; \
    unsigned short* d_ = As + (buf) * 16384 + (hf) * 8192 + t * 8;         \
    GLLDS(g_, d_);                                                         \
    GLLDS(g_ + (size_t)128 * KD, d_ + 4096);                               \
  } while (0)

#define STAGE_B(buf, nhf, tau) do {                                         \
    const unsigned short* g_ = Bg + (size_t)((nhf) * 32) * KD + (tau) * 64; \
    unsigned short* d_ = Bs + (buf) * 16384 + (nhf) * 8192 + t * 8;         \
    GLLDS(g_, d_);                                                          \
    GLLDS(g_ + (size_t)128 * KD, d_ + 4096);                                \
  } while (0)

// A-frag bank fill (8 x ds_read_b128), kk-major
#define LDA2_(buf, mh, bank) do {                                                 \
    const unsigned short* pa_ = As + (buf) * 16384 + (mh) * 8192 + wm * 4096 + lr * 64; \
    bank[0][0] = *(const bf16x8*)(pa_ + 0 * 1024 + ck0);                          \
    bank[0][1] = *(const bf16x8*)(pa_ + 1 * 1024 + ck0);                          \
    bank[0][2] = *(const bf16x8*)(pa_ + 2 * 1024 + ck0);                          \
    bank[0][3] = *(const bf16x8*)(pa_ + 3 * 1024 + ck0);                          \
    bank[1][0] = *(const bf16x8*)(pa_ + 0 * 1024 + ck1);                          \
    bank[1][1] = *(const bf16x8*)(pa_ + 1 * 1024 + ck1);                          \
    bank[1][2] = *(const bf16x8*)(pa_ + 2 * 1024 + ck1);                          \
    bank[1][3] = *(const bf16x8*)(pa_ + 3 * 1024 + ck1);                          \
  } while (0)

// B-frag bank fill (4 x ds_read_b128)
#define LDB_(buf, nhf, dst) do {                                                  \
    const unsigned short* pb_ = Bs + (buf) * 16384 + (nhf) * 8192 + wn * 2048 + lr * 64; \
    dst[0][0] = *(const bf16x8*)(pb_ + 0 * 1024 + ck0);                           \
    dst[0][1] = *(const bf16x8*)(pb_ + 1 * 1024 + ck0);                           \
    dst[1][0] = *(const bf16x8*)(pb_ + 0 * 1024 + ck1);                           \
    dst[1][1] = *(const bf16x8*)(pb_ + 1 * 1024 + ck1);                           \
  } while (0)

#define QUAD_(mh, nhf, abank, bsrc) do {                                          \
    __builtin_amdgcn_s_setprio(1);                                                \
    _Pragma("unroll") for (int kk_ = 0; kk_ < 2; ++kk_)                           \
    _Pragma("unroll") for (int mt_ = 0; mt_ < 4; ++mt_)                           \
    _Pragma("unroll") for (int nt_ = 0; nt_ < 2; ++nt_)                           \
      acc[mh][nhf][mt_][nt_] = __builtin_amdgcn_mfma_f32_16x16x32_bf16(           \
          abank[kk_][mt_], bsrc[kk_][nt_], acc[mh][nhf][mt_][nt_], 0, 0, 0);      \
    __builtin_amdgcn_s_setprio(0);                                                \
  } while (0)

#define SB_()  __builtin_amdgcn_sched_barrier(0)
#define BAR_() do { asm volatile("" ::: "memory");  __builtin_amdgcn_s_barrier(); \
                    asm volatile("" ::: "memory"); } while (0)
#define LGKM0_() do { asm volatile("s_waitcnt lgkmcnt(0)" ::: "memory"); SB_(); } while (0)
#define LGKM8_() do { asm volatile("s_waitcnt lgkmcnt(8)" ::: "memory"); SB_(); } while (0)
#define VM6_()   asm volatile("s_waitcnt vmcnt(6)" ::: "memory")

template <int OUT_BF16>
__global__ __launch_bounds__(512, 2) void gemm256(const unsigned short* __restrict__ A,
                                                  const unsigned short* __restrict__ B,
                                                  const float* __restrict__ bias,
                                                  void* __restrict__ Cptr,
                                                  int N) {
  // 128 KiB static LDS — 1 block/CU, 8 waves
  __shared__ __align__(16) unsigned short As[32768];
  __shared__ __align__(16) unsigned short Bs[32768];

  const int t   = threadIdx.x;
  const int nwg = gridDim.x;
  const int bid = blockIdx.x;
  // T1: bijective XCD swizzle (nwg % 8 == 0 for all our launches)
  const int wg  = (bid & 7) * (nwg >> 3) + (bid >> 3);
  const int bm  = wg & 15;             // M/256 == 16 always; bn-major chunks
  const int bn  = wg >> 4;             // -> per-XCD B-panel reuse in its L2

  const int w  = t >> 6, l = t & 63;
  const int wm = w >> 2, wn = w & 3;   // 2M x 4N wave grid
  const int lr = l & 15, lq = l >> 4;
  const int ck0 = (lq ^ (lr & 7)) * 8; // un-swizzled read chunk, kk=0
  const int ck1 = ck0 ^ 32;            // kk=1

  // staging: thread t covers row r8=t>>3, global chunk pre-swizzled so
  // LDS(row,c) = global chunk c^(row&7)  [G21: both sides]
  const int r8  = t >> 3;
  const int kcs = ((t & 7) ^ (r8 & 7)) * 8;
  const unsigned short* Ag = A + (size_t)(bm * 256 + r8) * KD + kcs;
  const unsigned short* Bg = B + (size_t)(bn * 256 + ((t >> 8) << 6) + (r8 & 31)) * KD + kcs;

  f32x4 acc[2][2][4][2] = {};          // [mh][nhf][mt][nt]
  bf16x8 afk0[2][4], afk1[2][4], bA[2][2], bB[2][2];

  // prologue: tile0 {S0,T0,T1,S1}, tile1 {S0,T0,T1}; vm6 retires tile0
  STAGE_A(0, 0, 0); STAGE_B(0, 0, 0); STAGE_B(0, 1, 0); STAGE_A(0, 1, 0);
  STAGE_A(1, 0, 1); STAGE_B(1, 0, 1); STAGE_B(1, 1, 1);
  VM6_();
  BAR_();

#pragma unroll 1
  for (int i = 0; i < NT2; ++i) {
    const int t1 = 2 * i + 1;
    const int t2 = (2 * i + 2 < 64) ? 2 * i + 2 : 63;   // clamp: dead stages
    const int t3 = (2 * i + 3 < 64) ? 2 * i + 3 : 63;

    // ---------- tile 2i (buf0) ----------
    // P1: rd A0,B0 (hidden under prev P8 MFMA drain)
    SB_();
    LDA2_(0, 0, afk0);
    LDB_(0, 0, bA);
    SB_();
    STAGE_A(1, 1, t1);
    BAR_();
    LGKM0_();
    QUAD_(0, 0, afk0, bA);
    SB_();
    BAR_();
    // P2: rd B1 then A1 (Q01 waits only B1 via lgkmcnt(8))
    SB_();
    LDB_(0, 1, bB);
    SB_();
    LDA2_(0, 1, afk1);
    SB_();
    STAGE_A(0, 0, t2);
    BAR_();
    LGKM8_();
    QUAD_(0, 1, afk0, bB);
    SB_();
    BAR_();
    // P3: no reads; afk1 drained under Q01
    STAGE_B(0, 0, t2);
    BAR_();
    LGKM0_();
    QUAD_(1, 1, afk1, bB);
    SB_();
    BAR_();
    // P4: no reads
    STAGE_B(0, 1, t2);
    BAR_();
    SB_();
    QUAD_(1, 0, afk1, bA);
    SB_();
    VM6_();
    BAR_();

    // ---------- tile 2i+1 (buf1) ----------
    // P5
    SB_();
    LDA2_(1, 0, afk0);
    LDB_(1, 0, bA);
    SB_();
    STAGE_A(0, 1, t2);
    BAR_();
    LGKM0_();
    QUAD_(0, 0, afk0, bA);
    SB_();
    BAR_();
    // P6
    SB_();
    LDB_(1, 1, bB);
    SB_();
    LDA2_(1, 1, afk1);
    SB_();
    STAGE_A(1, 0, t3);
    BAR_();
    LGKM8_();
    QUAD_(0, 1, afk0, bB);
    SB_();
    BAR_();
    // P7
    STAGE_B(1, 0, t3);
    BAR_();
    LGKM0_();
    QUAD_(1, 1, afk1, bB);
    SB_();
    BAR_();
    // P8
    STAGE_B(1, 1, t3);
    BAR_();
    SB_();
    QUAD_(1, 0, afk1, bA);
    SB_();
    VM6_();
    BAR_();
  }

  // drain in-flight LDS-DMA before waves exit
  asm volatile("s_waitcnt vmcnt(0)" ::: "memory");

  // epilogue: C/D layout col=lane&15, row=(lane>>4)*4+reg
  const int row0 = bm * 256 + wm * 128 + lq * 4;
  const int col0 = bn * 256 + wn * 64 + lr;
#pragma unroll
  for (int nhf = 0; nhf < 2; ++nhf)
#pragma unroll
    for (int nt = 0; nt < 2; ++nt) {
      const int col = col0 + nhf * 32 + nt * 16;
      const float bv = bias[col];
#pragma unroll
      for (int mh = 0; mh < 2; ++mh)
#pragma unroll
        for (int mt = 0; mt < 4; ++mt) {
          const int row = row0 + mh * 64 + mt * 16;
#pragma unroll
          for (int rg = 0; rg < 4; ++rg) {
            float v = acc[mh][nhf][mt][nt][rg] + bv;
            if (OUT_BF16)
              ((unsigned short*)Cptr)[(size_t)(row + rg) * N + col] = f2bf(v);
            else
              ((float*)Cptr)[(size_t)(row + rg) * N + col] = v;
          }
        }
    }
}

// ---------------- head-mixing attention, MFMA, one WAVE per (b,t) -------------
#define AST 72   // padded LDS row stride (elements)

__global__ __launch_bounds__(64) void attn_mfma(const unsigned short* __restrict__ qkv,
                                                unsigned short* __restrict__ y) {
  __shared__ __align__(16) unsigned short Ks[64 * AST];   // K, later P
  __shared__ __align__(16) unsigned short Vs[64 * AST];
  const int l  = threadIdx.x;
  const int lr = l & 15;
  const int lq = l >> 4;
  const size_t base = (size_t)blockIdx.x * 12288;

  // ---- stage K,V (coalesced 16B loads, padded LDS rows) ----
  {
    const int jr = l >> 3;          // 0..7
    const int cc = (l & 7) * 8;     // col chunk (elements)
#pragma unroll
    for (int c = 0; c < 8; ++c) {
      const int j = c * 8 + jr;
      *(uint4*)(Ks + j * AST + cc) = *(const uint4*)(qkv + base + 4096 + (size_t)j * 64 + cc);
      *(uint4*)(Vs + j * AST + cc) = *(const uint4*)(qkv + base + 8192 + (size_t)j * 64 + cc);
    }
  }

  // ---- Q A-frags direct from global ----
  bf16x8 aq[4][2];
#pragma unroll
  for (int it = 0; it < 4; ++it)
#pragma unroll
    for (int kk = 0; kk < 2; ++kk)
      aq[it][kk] = *(const bf16x8*)(qkv + base + (size_t)(it * 16 + lr) * 64 + kk * 32 + lq * 8);

  __syncthreads();

  // ---- S = Q K^T ----
  f32x4 acc[4][4] = {};
#pragma unroll
  for (int kk = 0; kk < 2; ++kk) {
    bf16x8 bk[4];
#pragma unroll
    for (int jt = 0; jt < 4; ++jt)
      bk[jt] = *(const bf16x8*)(Ks + (jt * 16 + lr) * AST + kk * 32 + lq * 8);
#pragma unroll
    for (int it = 0; it < 4; ++it)
#pragma unroll
      for (int jt = 0; jt < 4; ++jt)
        acc[it][jt] = __builtin_amdgcn_mfma_f32_16x16x32_bf16(aq[it][kk], bk[jt], acc[it][jt], 0, 0, 0);
  }

  // ---- mask + softmax in-register ----
#pragma unroll
  for (int it = 0; it < 4; ++it) {
#pragma unroll
    for (int rg = 0; rg < 4; ++rg) {
      const int row = it * 16 + lq * 4 + rg;
      float mx = -1e30f;
#pragma unroll
      for (int jt = 0; jt < 4; ++jt) {
        const int col = jt * 16 + lr;
        float s = acc[it][jt][rg] * 0.125f;
        s = (col <= row) ? s : -1e30f;
        acc[it][jt][rg] = s;
        mx = fmaxf(mx, s);
      }
#pragma unroll
      for (int d = 1; d < 16; d <<= 1)
        mx = fmaxf(mx, __shfl_xor(mx, d));
      float sum = 0.f;
#pragma unroll
      for (int jt = 0; jt < 4; ++jt) {
        float e = __expf(acc[it][jt][rg] - mx);
        acc[it][jt][rg] = e;
        sum += e;
      }
#pragma unroll
      for (int d = 1; d < 16; d <<= 1)
        sum += __shfl_xor(sum, d);
      const float inv = 1.f / sum;
#pragma unroll
      for (int jt = 0; jt < 4; ++jt)
        acc[it][jt][rg] *= inv;
    }
  }

  // ---- P -> LDS (bf16), reusing K slab ----
#pragma unroll
  for (int it = 0; it < 4; ++it)
#pragma unroll
    for (int rg = 0; rg < 4; ++rg) {
      const int row = it * 16 + lq * 4 + rg;
#pragma unroll
      for (int jt = 0; jt < 4; ++jt)
        Ks[row * AST + jt * 16 + lr] = f2bf(acc[it][jt][rg]);
    }
  __syncthreads();

  // ---- Y = P V ----
  f32x4 out[4][4] = {};
#pragma unroll
  for (int kk = 0; kk < 2; ++kk) {
    bf16x8 ap[4];
#pragma unroll
    for (int it = 0; it < 4; ++it)
      ap[it] = *(const bf16x8*)(Ks + (it * 16 + lr) * AST + kk * 32 + lq * 8);
#pragma unroll
    for (int dt = 0; dt < 4; ++dt) {
      ushort8 vt;
#pragma unroll
      for (int jj = 0; jj < 8; ++jj)
        vt[jj] = Vs[(kk * 32 + lq * 8 + jj) * AST + dt * 16 + lr];
      const bf16x8 bv = __builtin_bit_cast(bf16x8, vt);
#pragma unroll
      for (int it = 0; it < 4; ++it)
        out[it][dt] = __builtin_amdgcn_mfma_f32_16x16x32_bf16(ap[it], bv, out[it][dt], 0, 0, 0);
    }
  }

  // ---- epilogue: y[bt][i*64+d] bf16 ----
  unsigned short* yrow = y + (size_t)blockIdx.x * 4096;
#pragma unroll
  for (int it = 0; it < 4; ++it)
#pragma unroll
    for (int rg = 0; rg < 4; ++rg) {
      const int i = it * 16 + lq * 4 + rg;
#pragma unroll
      for (int dt = 0; dt < 4; ++dt)
        yrow[i * 64 + dt * 16 + lr] = f2bf(out[it][dt][rg]);
    }
}

// ---------------- launch ------------------------------------------------------
extern "C" void kernel_launch(void* const* d_in, const int* in_sizes, int n_in,
                              void* d_out, int out_size, void* d_ws, size_t ws_size,
                              hipStream_t stream) {
  const float* x  = (const float*)d_in[0];   // (64,64,4096)
  const float* Wa = (const float*)d_in[1];   // (12288,4096)
  const float* ba = (const float*)d_in[2];   // (12288)
  const float* Wp = (const float*)d_in[3];   // (4096,4096)
  const float* bp = (const float*)d_in[4];   // (4096)
  float* out = (float*)d_out;                // (64,64,4096) fp32

  // workspace layout (ushort elems), regions reused across phases:
  unsigned short* regA = (unsigned short*)d_ws;                 // 33.5 MB
  unsigned short* regB = regA + (size_t)16777216;               // 100.7 MB
  unsigned short* regC = regB + (size_t)50331648;               // 100.7 MB
  unsigned short* xb   = regA;
  unsigned short* Wab  = regB;
  unsigned short* qkvb = regC;
  unsigned short* Wpb  = regA;   // reuse after GEMM1 consumed xb
  unsigned short* yb   = regB;   // reuse after GEMM1 consumed Wab

  cvt_f32_bf16<<<(16777216 / 8) / 256, 256, 0, stream>>>(x, xb, 16777216 / 8);
  cvt_f32_bf16<<<(50331648 / 8) / 256, 256, 0, stream>>>(Wa, Wab, 50331648 / 8);

  // qkv = x @ Wa^T + ba   (M=4096, N=12288, K=4096), bf16 out; grid 768
  gemm256<1><<<dim3((M_TOK / 256) * (N_QKV / 256)), dim3(512), 0, stream>>>(
      xb, Wab, ba, (void*)qkvb, N_QKV);

  cvt_f32_bf16<<<(16777216 / 8) / 256, 256, 0, stream>>>(Wp, Wpb, 16777216 / 8);

  attn_mfma<<<M_TOK, 64, 0, stream>>>(qkvb, yb);

  // out = y @ Wp^T + bp   (M=4096, N=4096, K=4096), fp32 out; grid 256
  gemm256<0><<<dim3((M_TOK / 256) * (C_DIM / 256)), dim3(512), 0, stream>>>(
      yb, Wpb, bp, (void*)out, C_DIM);
}